// Round 12
// baseline (103108.374 us; speedup 1.0000x reference)
//
#include <hip/hip_runtime.h>
#include <math.h>

#define NPTS   8192
#define NB     2
#define NROWS  (NB*NPTS)       // 16384 points per cloud (B=2 x 8192)
#define ROWS_PER_WAVE  8
#define WAVES_PER_BLOCK 4
#define ROWS_PER_BLOCK (ROWS_PER_WAVE*WAVES_PER_BLOCK)   // 32
#define BLURF  0.001f
#define LOG2E  1.4426950408889634f
#define LN2F   0.6931471805599453f
#define BLOGF  (-9.010913347279288f)   // -log(8192)
#define DEFER_THR 8.0f
#define SKIP_THR  30.0f
#define PRUNE_K   40

typedef float v2f __attribute__((ext_vector_type(2)));

#if __has_builtin(__builtin_amdgcn_sqrtf)
#define FAST_SQRT(x) __builtin_amdgcn_sqrtf(x)
#else
#define FAST_SQRT(x) sqrtf(x)
#endif
#if __has_builtin(__builtin_amdgcn_exp2f)
#define RAW_EXP2(x) __builtin_amdgcn_exp2f(x)
#else
#define RAW_EXP2(x) exp2f(x)
#endif
#if __has_builtin(__builtin_amdgcn_logf)
#define RAW_LOG2(x) __builtin_amdgcn_logf(x)
#else
#define RAW_LOG2(x) log2f(x)
#endif
#if __has_builtin(__builtin_elementwise_max)
#define PKMAX(a,b) __builtin_elementwise_max(a,b)
#else
static __device__ __forceinline__ v2f PKMAX(v2f a, v2f b){ v2f r; r.x=fmaxf(a.x,b.x); r.y=fmaxf(a.y,b.y); return r; }
#endif

// ---- workspace layout (floats). Total = 16 + 12*NROWS = 196624 floats (786 KB)
#define WS_DIAM 0
#define WS_FA   16
#define WS_GA   (WS_FA + NROWS)
#define WS_XX   (WS_GA + NROWS)      // x-cloud coords SoA (X,Y,Z segments of NROWS)
#define WS_XY   (WS_XX + 3*NROWS)    // y-cloud coords SoA
#define WS_WXA  (WS_XY + 3*NROWS)    // folded f (cols of dir1), buffers A/B
#define WS_WXB  (WS_WXA + NROWS)
#define WS_WYA  (WS_WXB + NROWS)     // folded g (cols of dir0), buffers A/B
#define WS_WYB  (WS_WYA + NROWS)

// ---------------------------------------------------------------- diameter
__global__ __launch_bounds__(1024) void minmax_kernel(
    const float* __restrict__ x, const float* __restrict__ y,
    float* __restrict__ diam_out)
{
    int tid = threadIdx.x;
    float mx[3] = {-INFINITY, -INFINITY, -INFINITY};
    float mn[3] = { INFINITY,  INFINITY,  INFINITY};
    for (int p = tid; p < NROWS; p += 1024) {
        #pragma unroll
        for (int d = 0; d < 3; ++d) {
            float a = x[p*3+d], b = y[p*3+d];
            mx[d] = fmaxf(mx[d], fmaxf(a, b));
            mn[d] = fminf(mn[d], fminf(a, b));
        }
    }
    #pragma unroll
    for (int off = 32; off >= 1; off >>= 1) {
        #pragma unroll
        for (int d = 0; d < 3; ++d) {
            mx[d] = fmaxf(mx[d], __shfl_xor(mx[d], off));
            mn[d] = fminf(mn[d], __shfl_xor(mn[d], off));
        }
    }
    __shared__ float smx[16][3], smn[16][3];
    int wid = tid >> 6, lane = tid & 63;
    if (lane == 0) {
        #pragma unroll
        for (int d = 0; d < 3; ++d) { smx[wid][d] = mx[d]; smn[wid][d] = mn[d]; }
    }
    __syncthreads();
    if (tid == 0) {
        float dm = 0.0f;
        #pragma unroll
        for (int d = 0; d < 3; ++d) {
            float a = -INFINITY, b = INFINITY;
            for (int w = 0; w < 16; ++w) {
                a = fmaxf(a, smx[w][d]); b = fminf(b, smn[w][d]);
            }
            dm = fmaxf(dm, a - b);
        }
        diam_out[0] = dm;
    }
}

// ----------------- Morton-cell counting sort + SoA pack + W init ----------
static __device__ __forceinline__ int morton3(int cx, int cy, int cz){
    int m = 0;
    #pragma unroll
    for (int b = 0; b < 3; ++b)
        m |= (((cx>>b)&1)<<(3*b)) | (((cy>>b)&1)<<(3*b+1)) | (((cz>>b)&1)<<(3*b+2));
    return m;
}

__global__ __launch_bounds__(1024) void sort_pack_kernel(
    const float* __restrict__ x, const float* __restrict__ y,
    float* __restrict__ ws)
{
    // one block per (cloud, batch): cloud = blockIdx.x>>1, b = blockIdx.x&1
    const int g = blockIdx.x;
    const int cloud = g >> 1, b = g & 1;
    const float* src = (cloud ? y : x) + b * NPTS * 3;
    const int soa = cloud ? WS_XY : WS_XX;
    float* DX = ws + soa + b * NPTS;
    float* DY = ws + soa + NROWS + b * NPTS;
    float* DZ = ws + soa + 2*NROWS + b * NPTS;
    float* DW = ws + (cloud ? WS_WYA : WS_WXA) + b * NPTS;

    const int tid = threadIdx.x;
    __shared__ float wmn[16][3], wmx[16][3];
    __shared__ float sbb[6];            // min xyz, max xyz
    __shared__ int   hist[512];
    __shared__ int   offs[512];

    // per-group bbox
    float mn[3] = { INFINITY,  INFINITY,  INFINITY};
    float mx[3] = {-INFINITY, -INFINITY, -INFINITY};
    for (int p = tid; p < NPTS; p += 1024) {
        #pragma unroll
        for (int d = 0; d < 3; ++d) {
            float v = src[p*3+d];
            mn[d] = fminf(mn[d], v); mx[d] = fmaxf(mx[d], v);
        }
    }
    #pragma unroll
    for (int off = 32; off >= 1; off >>= 1) {
        #pragma unroll
        for (int d = 0; d < 3; ++d) {
            mn[d] = fminf(mn[d], __shfl_xor(mn[d], off));
            mx[d] = fmaxf(mx[d], __shfl_xor(mx[d], off));
        }
    }
    int wid = tid >> 6, lane = tid & 63;
    if (lane == 0) {
        #pragma unroll
        for (int d = 0; d < 3; ++d) { wmn[wid][d] = mn[d]; wmx[wid][d] = mx[d]; }
    }
    if (tid < 512) hist[tid] = 0;
    __syncthreads();
    if (tid == 0) {
        #pragma unroll
        for (int d = 0; d < 3; ++d) {
            float a = INFINITY, bx = -INFINITY;
            for (int w = 0; w < 16; ++w) { a = fminf(a, wmn[w][d]); bx = fmaxf(bx, wmx[w][d]); }
            sbb[d] = a; sbb[3+d] = bx;
        }
    }
    __syncthreads();
    float bmn0 = sbb[0], bmn1 = sbb[1], bmn2 = sbb[2];
    float sc0 = 7.999f / fmaxf(sbb[3]-sbb[0], 1e-9f);
    float sc1 = 7.999f / fmaxf(sbb[4]-sbb[1], 1e-9f);
    float sc2 = 7.999f / fmaxf(sbb[5]-sbb[2], 1e-9f);

    // histogram
    for (int p = tid; p < NPTS; p += 1024) {
        int cx = (int)((src[p*3+0]-bmn0)*sc0);
        int cy = (int)((src[p*3+1]-bmn1)*sc1);
        int cz = (int)((src[p*3+2]-bmn2)*sc2);
        cx = min(max(cx,0),7); cy = min(max(cy,0),7); cz = min(max(cz,0),7);
        atomicAdd(&hist[morton3(cx,cy,cz)], 1);
    }
    __syncthreads();
    if (tid == 0) {
        int run = 0;
        for (int c = 0; c < 512; ++c) { offs[c] = run; run += hist[c]; }
    }
    __syncthreads();
    // scatter (recompute cell identically)
    for (int p = tid; p < NPTS; p += 1024) {
        float px = src[p*3+0], py = src[p*3+1], pz = src[p*3+2];
        int cx = (int)((px-bmn0)*sc0);
        int cy = (int)((py-bmn1)*sc1);
        int cz = (int)((pz-bmn2)*sc2);
        cx = min(max(cx,0),7); cy = min(max(cy,0),7); cz = min(max(cz,0),7);
        int pos = atomicAdd(&offs[morton3(cx,cy,cz)], 1);
        DX[pos] = px; DY[pos] = py; DZ[pos] = pz;
        DW[pos] = BLOGF * LOG2E;
    }
}

// ------------------------------------------------------------- softmin pass
// out[b,i] = -eps*ln2*log2( sum_j 2^{W[j] - ||p_i - q_j||*log2e/eps} )
// PRUNE=1: per-128-col quantum, skip sqrt/exp2 when all pairs provably
//          satisfy w < m - SKIP_THR (checked in squared-distance domain).
template<int PRUNE>
__global__ __launch_bounds__(256, 3) void softmin_kernel(
    float* __restrict__ ws, int cur,
    float scale_k, float scale_next, int do_avg)
{
    const int dir = blockIdx.z;

    const float diam      = ws[WS_DIAM];
    const float eps       = fmaxf(diam * scale_k, BLURF);
    const float nie2      = -LOG2E / eps;
    const float ipt       = eps * LN2F;           // 1/(-nie2)
    const float eps_next  = fmaxf(diam * scale_next, BLURF);
    const float ien_log2e = LOG2E / eps_next;

    const int tid = threadIdx.x, lane = tid & 63, wid = tid >> 6;
    const int i0  = blockIdx.x * ROWS_PER_BLOCK;
    const int b   = i0 >> 13;
    const int rowbase = i0 + wid * ROWS_PER_WAVE;

    // rows from own-cloud SoA (permuted space)
    const int rbase = dir ? WS_XY : WS_XX;
    const float* RX = ws + rbase;
    const float* RY = ws + rbase + NROWS;
    const float* RZ = ws + rbase + 2*NROWS;
    // cols from opposite-cloud SoA
    const int cbase = dir ? WS_XX : WS_XY;
    const v2f* CX = ((const v2f*)(ws + cbase          )) + b*(NPTS/2);
    const v2f* CY = ((const v2f*)(ws + cbase +   NROWS)) + b*(NPTS/2);
    const v2f* CZ = ((const v2f*)(ws + cbase + 2*NROWS)) + b*(NPTS/2);
    const int wcur_off = dir ? (cur ? WS_WXB : WS_WXA) : (cur ? WS_WYB : WS_WYA);
    const int wnxt_off = dir ? (cur ? WS_WYA : WS_WYB) : (cur ? WS_WXA : WS_WXB);
    const v2f* CW = ((const v2f*)(ws + wcur_off)) + b*(NPTS/2);
    float* Wnxt = ws + wnxt_off;
    float* outf = ws + (dir ? WS_GA : WS_FA);

    float px[ROWS_PER_WAVE], py[ROWS_PER_WAVE], pz[ROWS_PER_WAVE];
    #pragma unroll
    for (int r = 0; r < ROWS_PER_WAVE; ++r) {
        px[r] = RX[rowbase + r]; py[r] = RY[rowbase + r]; pz[r] = RZ[rowbase + r];
    }

    v2f m2[ROWS_PER_WAVE], s2[ROWS_PER_WAVE];
    #pragma unroll
    for (int r = 0; r < ROWS_PER_WAVE; ++r) {
        m2[r] = (v2f){-INFINITY,-INFINITY}; s2[r] = (v2f){0.0f,0.0f};
    }

    const v2f nie2v = {nie2, nie2};
    const v2f iptv  = {ipt, ipt};
    const v2f thr30v = {SKIP_THR, SKIP_THR};
    const v2f zv = {0.0f, 0.0f};

    for (int c0 = 0; c0 < NPTS/2; c0 += 256) {     // 512 cols per iter
        v2f Xc[4], Yc[4], Zc[4], Wc[4];
        #pragma unroll
        for (int k = 0; k < 4; ++k) {
            int idx = c0 + k*64 + lane;
            Xc[k] = CX[idx]; Yc[k] = CY[idx]; Zc[k] = CZ[idx]; Wc[k] = CW[idx];
        }
        if constexpr (PRUNE) {
            #pragma unroll
            for (int k = 0; k < 4; ++k) {     // 128-col skip quantum
                v2f sqv[ROWS_PER_WAVE];
                float rowmet = -1.0f;
                #pragma unroll
                for (int r = 0; r < ROWS_PER_WAVE; ++r) {
                    v2f dx = Xc[k] - (v2f){px[r],px[r]};
                    v2f dy = Yc[k] - (v2f){py[r],py[r]};
                    v2f dz = Zc[k] - (v2f){pz[r],pz[r]};
                    v2f sq = dx*dx + dy*dy + dz*dz;
                    sqv[r] = sq;
                    v2f thr = (Wc[k] - m2[r] + thr30v) * iptv;
                    thr = PKMAX(thr, zv);
                    v2f met = thr*thr - sq;
                    rowmet = fmaxf(rowmet, fmaxf(met.x, met.y));
                }
                if (__any(rowmet > 0.0f)) {
                    #pragma unroll
                    for (int r = 0; r < ROWS_PER_WAVE; ++r) {
                        v2f c2; c2.x = FAST_SQRT(sqv[r].x); c2.y = FAST_SQRT(sqv[r].y);
                        v2f w2 = c2 * nie2v + Wc[k];
                        bool need = (w2.x > m2[r].x + DEFER_THR) | (w2.y > m2[r].y + DEFER_THR);
                        if (__any(need)) {
                            v2f mu = PKMAX(m2[r], w2);
                            v2f dm = m2[r] - mu;
                            v2f sc; sc.x = RAW_EXP2(dm.x); sc.y = RAW_EXP2(dm.y);
                            s2[r] = s2[r] * sc;
                            m2[r] = mu;
                        }
                        v2f e = w2 - m2[r];
                        v2f ve; ve.x = RAW_EXP2(e.x); ve.y = RAW_EXP2(e.y);
                        s2[r] = s2[r] + ve;
                    }
                }
            }
        } else {
            #pragma unroll
            for (int r = 0; r < ROWS_PER_WAVE; ++r) {
                const v2f prx = {px[r], px[r]}, pry = {py[r], py[r]}, prz = {pz[r], pz[r]};
                v2f w2[4];
                #pragma unroll
                for (int k = 0; k < 4; ++k) {
                    v2f dx = Xc[k] - prx, dy = Yc[k] - pry, dz = Zc[k] - prz;
                    v2f sq = dx*dx + dy*dy + dz*dz;
                    v2f c2; c2.x = FAST_SQRT(sq.x); c2.y = FAST_SQRT(sq.y);
                    w2[k] = c2 * nie2v + Wc[k];
                }
                v2f gm = PKMAX(PKMAX(w2[0], w2[1]), PKMAX(w2[2], w2[3]));
                bool need = (gm.x > m2[r].x + DEFER_THR) | (gm.y > m2[r].y + DEFER_THR);
                if (__any(need)) {
                    v2f mu = PKMAX(m2[r], gm);
                    v2f dm = m2[r] - mu;
                    v2f sc; sc.x = RAW_EXP2(dm.x); sc.y = RAW_EXP2(dm.y);
                    s2[r] = s2[r] * sc;
                    m2[r] = mu;
                }
                v2f e0 = w2[0] - m2[r], e1 = w2[1] - m2[r], e2 = w2[2] - m2[r], e3 = w2[3] - m2[r];
                v2f v0, v1, v2, v3;
                v0.x = RAW_EXP2(e0.x); v0.y = RAW_EXP2(e0.y);
                v1.x = RAW_EXP2(e1.x); v1.y = RAW_EXP2(e1.y);
                v2.x = RAW_EXP2(e2.x); v2.y = RAW_EXP2(e2.y);
                v3.x = RAW_EXP2(e3.x); v3.y = RAW_EXP2(e3.y);
                s2[r] = s2[r] + ((v0 + v1) + (v2 + v3));
            }
        }
    }

    // merge packed halves, then 64-lane butterfly
    #pragma unroll
    for (int r = 0; r < ROWS_PER_WAVE; ++r) {
        float mm = fmaxf(m2[r].x, m2[r].y);
        float ss = s2[r].x * RAW_EXP2(m2[r].x - mm) + s2[r].y * RAW_EXP2(m2[r].y - mm);
        #pragma unroll
        for (int off = 32; off >= 1; off >>= 1) {
            float mo = __shfl_xor(mm, off);
            float so = __shfl_xor(ss, off);
            float mu = fmaxf(mm, mo);
            ss = fmaf(ss, RAW_EXP2(mm-mu), so * RAW_EXP2(mo-mu));
            mm = mu;
        }
        if (lane == 0) {
            float res = -eps * LN2F * (mm + RAW_LOG2(ss));
            int oidx = rowbase + r;
            if (do_avg) res = 0.5f * (outf[oidx] + res);   // element owned by this thread
            outf[oidx] = res;
            Wnxt[oidx] = fmaf(res, ien_log2e, BLOGF * LOG2E);  // fold for next pass
        }
    }
}

// ----------------------------------------------------------------- reduce
__global__ __launch_bounds__(1024) void reduce_kernel(
    const float* __restrict__ ws, float* __restrict__ out)
{
    const float* f = ws + WS_FA;
    const float* g = ws + WS_GA;
    int tid = threadIdx.x;
    float acc = 0.0f;
    for (int i = tid; i < NROWS; i += 1024) acc += f[i] + g[i];
    #pragma unroll
    for (int off = 32; off >= 1; off >>= 1) acc += __shfl_xor(acc, off);
    __shared__ float sw[16];
    int wid = tid >> 6, lane = tid & 63;
    if (lane == 0) sw[wid] = acc;
    __syncthreads();
    if (tid == 0) {
        float t = 0.0f;
        for (int w = 0; w < 16; ++w) t += sw[w];
        out[0] = t * (1.0f / (float)NROWS);   // mean over B of (sum a*f + sum b*g)
    }
}

// ----------------------------------------------------------------- launch
extern "C" void kernel_launch(void* const* d_in, const int* in_sizes, int n_in,
                              void* d_out, int out_size, void* d_ws, size_t ws_size,
                              hipStream_t stream)
{
    const float* x = (const float*)d_in[0];
    const float* y = (const float*)d_in[1];
    float* out = (float*)d_out;
    float* ws  = (float*)d_ws;

    minmax_kernel<<<1, 1024, 0, stream>>>(x, y, ws + WS_DIAM);
    sort_pack_kernel<<<4, 1024, 0, stream>>>(x, y, ws);

    dim3 sgrid(NROWS/ROWS_PER_BLOCK, 1, 2);   // 512 x 1 x 2
    int cur = 0;

    // init: f0,g0 at eps0; epilogue folds with eps of step 0 (= eps0 again)
    softmin_kernel<0><<<sgrid, 256, 0, stream>>>(ws, cur, 1.0f, 1.0f, 0);
    cur ^= 1;

    // 96 Jacobi steps; step k at eps_k = max(diam*0.9^k, blur); fold for k+1
    double sk = 1.0;
    for (int k = 0; k < 96; ++k) {
        float sn = (k < 95) ? (float)(sk * 0.9) : 0.0f;   // last folds at blur
        if (k >= PRUNE_K)
            softmin_kernel<1><<<sgrid, 256, 0, stream>>>(ws, cur, (float)sk, sn, 1);
        else
            softmin_kernel<0><<<sgrid, 256, 0, stream>>>(ws, cur, (float)sk, sn, 1);
        cur ^= 1;
        sk *= 0.9;
    }

    // final extrapolation at eps = blur (fold output unused)
    softmin_kernel<1><<<sgrid, 256, 0, stream>>>(ws, cur, 0.0f, 0.0f, 0);

    reduce_kernel<<<1, 1024, 0, stream>>>(ws, out);
}

// Round 13
// 19582.794 us; speedup vs baseline: 5.2653x; 5.2653x over previous
//
#include <hip/hip_runtime.h>
#include <math.h>

#define NPTS   8192
#define NB     2
#define NROWS  (NB*NPTS)       // 16384 points per cloud (B=2 x 8192)
#define ROWS_PER_WAVE  8
#define WAVES_PER_BLOCK 4
#define ROWS_PER_BLOCK (ROWS_PER_WAVE*WAVES_PER_BLOCK)   // 32
#define BLURF  0.001f
#define LOG2E  1.4426950408889634f
#define LN2F   0.6931471805599453f
#define BLOGF  (-9.010913347279288f)   // -log(8192)
#define DEFER_THR 8.0f
#define SKIP_THR  30.0f
#define PRUNE_K   48

typedef float v2f __attribute__((ext_vector_type(2)));

#if __has_builtin(__builtin_amdgcn_sqrtf)
#define FAST_SQRT(x) __builtin_amdgcn_sqrtf(x)
#else
#define FAST_SQRT(x) sqrtf(x)
#endif
#if __has_builtin(__builtin_amdgcn_exp2f)
#define RAW_EXP2(x) __builtin_amdgcn_exp2f(x)
#else
#define RAW_EXP2(x) exp2f(x)
#endif
#if __has_builtin(__builtin_amdgcn_logf)
#define RAW_LOG2(x) __builtin_amdgcn_logf(x)
#else
#define RAW_LOG2(x) log2f(x)
#endif
#if __has_builtin(__builtin_elementwise_max)
#define PKMAX(a,b) __builtin_elementwise_max(a,b)
#else
static __device__ __forceinline__ v2f PKMAX(v2f a, v2f b){ v2f r; r.x=fmaxf(a.x,b.x); r.y=fmaxf(a.y,b.y); return r; }
#endif

// ---- workspace layout (floats). Total = 16 + 12*NROWS = 196624 floats (786 KB)
#define WS_DIAM 0
#define WS_FA   16
#define WS_GA   (WS_FA + NROWS)
#define WS_XX   (WS_GA + NROWS)      // x-cloud coords SoA (X,Y,Z segments of NROWS)
#define WS_XY   (WS_XX + 3*NROWS)    // y-cloud coords SoA
#define WS_WXA  (WS_XY + 3*NROWS)    // folded f (cols of dir1), buffers A/B
#define WS_WXB  (WS_WXA + NROWS)
#define WS_WYA  (WS_WXB + NROWS)     // folded g (cols of dir0), buffers A/B
#define WS_WYB  (WS_WYA + NROWS)

// ---------------------------------------------------------------- diameter
__global__ __launch_bounds__(1024) void minmax_kernel(
    const float* __restrict__ x, const float* __restrict__ y,
    float* __restrict__ diam_out)
{
    int tid = threadIdx.x;
    float mx[3] = {-INFINITY, -INFINITY, -INFINITY};
    float mn[3] = { INFINITY,  INFINITY,  INFINITY};
    for (int p = tid; p < NROWS; p += 1024) {
        #pragma unroll
        for (int d = 0; d < 3; ++d) {
            float a = x[p*3+d], b = y[p*3+d];
            mx[d] = fmaxf(mx[d], fmaxf(a, b));
            mn[d] = fminf(mn[d], fminf(a, b));
        }
    }
    #pragma unroll
    for (int off = 32; off >= 1; off >>= 1) {
        #pragma unroll
        for (int d = 0; d < 3; ++d) {
            mx[d] = fmaxf(mx[d], __shfl_xor(mx[d], off));
            mn[d] = fminf(mn[d], __shfl_xor(mn[d], off));
        }
    }
    __shared__ float smx[16][3], smn[16][3];
    int wid = tid >> 6, lane = tid & 63;
    if (lane == 0) {
        #pragma unroll
        for (int d = 0; d < 3; ++d) { smx[wid][d] = mx[d]; smn[wid][d] = mn[d]; }
    }
    __syncthreads();
    if (tid == 0) {
        float dm = 0.0f;
        #pragma unroll
        for (int d = 0; d < 3; ++d) {
            float a = -INFINITY, b = INFINITY;
            for (int w = 0; w < 16; ++w) {
                a = fmaxf(a, smx[w][d]); b = fminf(b, smn[w][d]);
            }
            dm = fmaxf(dm, a - b);
        }
        diam_out[0] = dm;
    }
}

// ----------------- Morton-cell counting sort + SoA pack + W init ----------
static __device__ __forceinline__ int morton3(int cx, int cy, int cz){
    int m = 0;
    #pragma unroll
    for (int b = 0; b < 3; ++b)
        m |= (((cx>>b)&1)<<(3*b)) | (((cy>>b)&1)<<(3*b+1)) | (((cz>>b)&1)<<(3*b+2));
    return m;
}

__global__ __launch_bounds__(1024) void sort_pack_kernel(
    const float* __restrict__ x, const float* __restrict__ y,
    float* __restrict__ ws)
{
    // one block per (cloud, batch): cloud = blockIdx.x>>1, b = blockIdx.x&1
    const int g = blockIdx.x;
    const int cloud = g >> 1, b = g & 1;
    const float* src = (cloud ? y : x) + b * NPTS * 3;
    const int soa = cloud ? WS_XY : WS_XX;
    float* DX = ws + soa + b * NPTS;
    float* DY = ws + soa + NROWS + b * NPTS;
    float* DZ = ws + soa + 2*NROWS + b * NPTS;
    float* DW = ws + (cloud ? WS_WYA : WS_WXA) + b * NPTS;

    const int tid = threadIdx.x;
    __shared__ float wmn[16][3], wmx[16][3];
    __shared__ float sbb[6];            // min xyz, max xyz
    __shared__ int   hist[512];
    __shared__ int   offs[512];

    float mn[3] = { INFINITY,  INFINITY,  INFINITY};
    float mx[3] = {-INFINITY, -INFINITY, -INFINITY};
    for (int p = tid; p < NPTS; p += 1024) {
        #pragma unroll
        for (int d = 0; d < 3; ++d) {
            float v = src[p*3+d];
            mn[d] = fminf(mn[d], v); mx[d] = fmaxf(mx[d], v);
        }
    }
    #pragma unroll
    for (int off = 32; off >= 1; off >>= 1) {
        #pragma unroll
        for (int d = 0; d < 3; ++d) {
            mn[d] = fminf(mn[d], __shfl_xor(mn[d], off));
            mx[d] = fmaxf(mx[d], __shfl_xor(mx[d], off));
        }
    }
    int wid = tid >> 6, lane = tid & 63;
    if (lane == 0) {
        #pragma unroll
        for (int d = 0; d < 3; ++d) { wmn[wid][d] = mn[d]; wmx[wid][d] = mx[d]; }
    }
    if (tid < 512) hist[tid] = 0;
    __syncthreads();
    if (tid == 0) {
        #pragma unroll
        for (int d = 0; d < 3; ++d) {
            float a = INFINITY, bx = -INFINITY;
            for (int w = 0; w < 16; ++w) { a = fminf(a, wmn[w][d]); bx = fmaxf(bx, wmx[w][d]); }
            sbb[d] = a; sbb[3+d] = bx;
        }
    }
    __syncthreads();
    float bmn0 = sbb[0], bmn1 = sbb[1], bmn2 = sbb[2];
    float sc0 = 7.999f / fmaxf(sbb[3]-sbb[0], 1e-9f);
    float sc1 = 7.999f / fmaxf(sbb[4]-sbb[1], 1e-9f);
    float sc2 = 7.999f / fmaxf(sbb[5]-sbb[2], 1e-9f);

    for (int p = tid; p < NPTS; p += 1024) {
        int cx = (int)((src[p*3+0]-bmn0)*sc0);
        int cy = (int)((src[p*3+1]-bmn1)*sc1);
        int cz = (int)((src[p*3+2]-bmn2)*sc2);
        cx = min(max(cx,0),7); cy = min(max(cy,0),7); cz = min(max(cz,0),7);
        atomicAdd(&hist[morton3(cx,cy,cz)], 1);
    }
    __syncthreads();
    if (tid == 0) {
        int run = 0;
        for (int c = 0; c < 512; ++c) { offs[c] = run; run += hist[c]; }
    }
    __syncthreads();
    for (int p = tid; p < NPTS; p += 1024) {
        float px = src[p*3+0], py = src[p*3+1], pz = src[p*3+2];
        int cx = (int)((px-bmn0)*sc0);
        int cy = (int)((py-bmn1)*sc1);
        int cz = (int)((pz-bmn2)*sc2);
        cx = min(max(cx,0),7); cy = min(max(cy,0),7); cz = min(max(cz,0),7);
        int pos = atomicAdd(&offs[morton3(cx,cy,cz)], 1);
        DX[pos] = px; DY[pos] = py; DZ[pos] = pz;
        DW[pos] = BLOGF * LOG2E;
    }
}

// ------------------------------------------------------------- softmin pass
// out[b,i] = -eps*ln2*log2( sum_j 2^{W[j] - ||p_i - q_j||*log2e/eps} )
// PRUNE=1: per-128-col quantum squared-domain check; skipped quanta provably
//          contribute < 2^-30 relative. Register-lean: no state live across
//          the branch except m2/s2/cr; sq recomputed on survive.
template<int PRUNE>
__global__ __launch_bounds__(256, 4) void softmin_kernel(
    float* __restrict__ ws, int cur,
    float scale_k, float scale_next, int do_avg)
{
    const int dir = blockIdx.z;

    const float diam      = ws[WS_DIAM];
    const float eps       = fmaxf(diam * scale_k, BLURF);
    const float nie2      = -LOG2E / eps;
    const float ipt       = eps * LN2F;
    const float eps_next  = fmaxf(diam * scale_next, BLURF);
    const float ien_log2e = LOG2E / eps_next;

    const int tid = threadIdx.x, lane = tid & 63, wid = tid >> 6;
    const int i0  = blockIdx.x * ROWS_PER_BLOCK;
    const int b   = i0 >> 13;
    const int rowbase = i0 + wid * ROWS_PER_WAVE;

    const int rbase = dir ? WS_XY : WS_XX;
    const float* RX = ws + rbase;
    const float* RY = ws + rbase + NROWS;
    const float* RZ = ws + rbase + 2*NROWS;
    const int cbase = dir ? WS_XX : WS_XY;
    const v2f* CX = ((const v2f*)(ws + cbase          )) + b*(NPTS/2);
    const v2f* CY = ((const v2f*)(ws + cbase +   NROWS)) + b*(NPTS/2);
    const v2f* CZ = ((const v2f*)(ws + cbase + 2*NROWS)) + b*(NPTS/2);
    const int wcur_off = dir ? (cur ? WS_WXB : WS_WXA) : (cur ? WS_WYB : WS_WYA);
    const int wnxt_off = dir ? (cur ? WS_WYA : WS_WYB) : (cur ? WS_WXA : WS_WXB);
    const v2f* CW = ((const v2f*)(ws + wcur_off)) + b*(NPTS/2);
    float* Wnxt = ws + wnxt_off;
    float* outf = ws + (dir ? WS_GA : WS_FA);

    float px[ROWS_PER_WAVE], py[ROWS_PER_WAVE], pz[ROWS_PER_WAVE];
    #pragma unroll
    for (int r = 0; r < ROWS_PER_WAVE; ++r) {
        px[r] = RX[rowbase + r]; py[r] = RY[rowbase + r]; pz[r] = RZ[rowbase + r];
    }

    v2f m2[ROWS_PER_WAVE], s2[ROWS_PER_WAVE];
    #pragma unroll
    for (int r = 0; r < ROWS_PER_WAVE; ++r) {
        m2[r] = (v2f){-INFINITY,-INFINITY}; s2[r] = (v2f){0.0f,0.0f};
    }

    const v2f nie2v = {nie2, nie2};
    const v2f iptv  = {ipt, ipt};
    const v2f thr30v = {SKIP_THR, SKIP_THR};
    const v2f zv = {0.0f, 0.0f};

    if constexpr (PRUNE) {
        // cr[r] = (SKIP_THR - m2[r]) * ipt, maintained on m2 change only
        v2f cr[ROWS_PER_WAVE];
        #pragma unroll
        for (int r = 0; r < ROWS_PER_WAVE; ++r) cr[r] = (v2f){INFINITY, INFINITY};

        for (int kk = 0; kk < NPTS/2; kk += 64) {   // 128 cols per quantum
            const int idx = kk + lane;
            const v2f Xk = CX[idx], Yk = CY[idx], Zk = CZ[idx], Wk = CW[idx];
            const v2f ak = Wk * iptv;
            // squared-domain check, no trans, nothing extra live after
            v2f qmet = {-1.0f, -1.0f};
            #pragma unroll
            for (int r = 0; r < ROWS_PER_WAVE; ++r) {
                v2f dx = Xk - (v2f){px[r],px[r]};
                v2f dy = Yk - (v2f){py[r],py[r]};
                v2f dz = Zk - (v2f){pz[r],pz[r]};
                v2f sq = dx*dx + dy*dy + dz*dz;
                v2f t  = PKMAX(ak + cr[r], zv);
                qmet = PKMAX(qmet, t*t - sq);
            }
            if (__any(fmaxf(qmet.x, qmet.y) > 0.0f)) {
                #pragma unroll
                for (int r = 0; r < ROWS_PER_WAVE; ++r) {
                    v2f dx = Xk - (v2f){px[r],px[r]};
                    v2f dy = Yk - (v2f){py[r],py[r]};
                    v2f dz = Zk - (v2f){pz[r],pz[r]};
                    v2f sq = dx*dx + dy*dy + dz*dz;
                    v2f c2; c2.x = FAST_SQRT(sq.x); c2.y = FAST_SQRT(sq.y);
                    v2f w2 = c2 * nie2v + Wk;
                    bool need = (w2.x > m2[r].x + DEFER_THR) | (w2.y > m2[r].y + DEFER_THR);
                    if (__any(need)) {
                        v2f mu = PKMAX(m2[r], w2);
                        v2f dm = m2[r] - mu;
                        v2f sc; sc.x = RAW_EXP2(dm.x); sc.y = RAW_EXP2(dm.y);
                        s2[r] = s2[r] * sc;
                        m2[r] = mu;
                        cr[r] = (thr30v - mu) * iptv;
                    }
                    v2f e = w2 - m2[r];
                    v2f ve; ve.x = RAW_EXP2(e.x); ve.y = RAW_EXP2(e.y);
                    s2[r] = s2[r] + ve;
                }
            }
        }
    } else {
        for (int c0 = 0; c0 < NPTS/2; c0 += 256) {     // 512 cols per iter
            v2f Xc[4], Yc[4], Zc[4], Wc[4];
            #pragma unroll
            for (int k = 0; k < 4; ++k) {
                int idx = c0 + k*64 + lane;
                Xc[k] = CX[idx]; Yc[k] = CY[idx]; Zc[k] = CZ[idx]; Wc[k] = CW[idx];
            }
            #pragma unroll
            for (int r = 0; r < ROWS_PER_WAVE; ++r) {
                const v2f prx = {px[r], px[r]}, pry = {py[r], py[r]}, prz = {pz[r], pz[r]};
                v2f w2[4];
                #pragma unroll
                for (int k = 0; k < 4; ++k) {
                    v2f dx = Xc[k] - prx, dy = Yc[k] - pry, dz = Zc[k] - prz;
                    v2f sq = dx*dx + dy*dy + dz*dz;
                    v2f c2; c2.x = FAST_SQRT(sq.x); c2.y = FAST_SQRT(sq.y);
                    w2[k] = c2 * nie2v + Wc[k];
                }
                v2f gm = PKMAX(PKMAX(w2[0], w2[1]), PKMAX(w2[2], w2[3]));
                bool need = (gm.x > m2[r].x + DEFER_THR) | (gm.y > m2[r].y + DEFER_THR);
                if (__any(need)) {
                    v2f mu = PKMAX(m2[r], gm);
                    v2f dm = m2[r] - mu;
                    v2f sc; sc.x = RAW_EXP2(dm.x); sc.y = RAW_EXP2(dm.y);
                    s2[r] = s2[r] * sc;
                    m2[r] = mu;
                }
                v2f e0 = w2[0] - m2[r], e1 = w2[1] - m2[r], e2 = w2[2] - m2[r], e3 = w2[3] - m2[r];
                v2f v0, v1, v2, v3;
                v0.x = RAW_EXP2(e0.x); v0.y = RAW_EXP2(e0.y);
                v1.x = RAW_EXP2(e1.x); v1.y = RAW_EXP2(e1.y);
                v2.x = RAW_EXP2(e2.x); v2.y = RAW_EXP2(e2.y);
                v3.x = RAW_EXP2(e3.x); v3.y = RAW_EXP2(e3.y);
                s2[r] = s2[r] + ((v0 + v1) + (v2 + v3));
            }
        }
    }

    // merge packed halves, then 64-lane butterfly
    #pragma unroll
    for (int r = 0; r < ROWS_PER_WAVE; ++r) {
        float mm = fmaxf(m2[r].x, m2[r].y);
        float ss = s2[r].x * RAW_EXP2(m2[r].x - mm) + s2[r].y * RAW_EXP2(m2[r].y - mm);
        #pragma unroll
        for (int off = 32; off >= 1; off >>= 1) {
            float mo = __shfl_xor(mm, off);
            float so = __shfl_xor(ss, off);
            float mu = fmaxf(mm, mo);
            ss = fmaf(ss, RAW_EXP2(mm-mu), so * RAW_EXP2(mo-mu));
            mm = mu;
        }
        if (lane == 0) {
            float res = -eps * LN2F * (mm + RAW_LOG2(ss));
            int oidx = rowbase + r;
            if (do_avg) res = 0.5f * (outf[oidx] + res);   // element owned by this thread
            outf[oidx] = res;
            Wnxt[oidx] = fmaf(res, ien_log2e, BLOGF * LOG2E);  // fold for next pass
        }
    }
}

// ----------------------------------------------------------------- reduce
__global__ __launch_bounds__(1024) void reduce_kernel(
    const float* __restrict__ ws, float* __restrict__ out)
{
    const float* f = ws + WS_FA;
    const float* g = ws + WS_GA;
    int tid = threadIdx.x;
    float acc = 0.0f;
    for (int i = tid; i < NROWS; i += 1024) acc += f[i] + g[i];
    #pragma unroll
    for (int off = 32; off >= 1; off >>= 1) acc += __shfl_xor(acc, off);
    __shared__ float sw[16];
    int wid = tid >> 6, lane = tid & 63;
    if (lane == 0) sw[wid] = acc;
    __syncthreads();
    if (tid == 0) {
        float t = 0.0f;
        for (int w = 0; w < 16; ++w) t += sw[w];
        out[0] = t * (1.0f / (float)NROWS);   // mean over B of (sum a*f + sum b*g)
    }
}

// ----------------------------------------------------------------- launch
extern "C" void kernel_launch(void* const* d_in, const int* in_sizes, int n_in,
                              void* d_out, int out_size, void* d_ws, size_t ws_size,
                              hipStream_t stream)
{
    const float* x = (const float*)d_in[0];
    const float* y = (const float*)d_in[1];
    float* out = (float*)d_out;
    float* ws  = (float*)d_ws;

    minmax_kernel<<<1, 1024, 0, stream>>>(x, y, ws + WS_DIAM);
    sort_pack_kernel<<<4, 1024, 0, stream>>>(x, y, ws);

    dim3 sgrid(NROWS/ROWS_PER_BLOCK, 1, 2);   // 512 x 1 x 2
    int cur = 0;

    softmin_kernel<0><<<sgrid, 256, 0, stream>>>(ws, cur, 1.0f, 1.0f, 0);
    cur ^= 1;

    double sk = 1.0;
    for (int k = 0; k < 96; ++k) {
        float sn = (k < 95) ? (float)(sk * 0.9) : 0.0f;   // last folds at blur
        if (k >= PRUNE_K)
            softmin_kernel<1><<<sgrid, 256, 0, stream>>>(ws, cur, (float)sk, sn, 1);
        else
            softmin_kernel<0><<<sgrid, 256, 0, stream>>>(ws, cur, (float)sk, sn, 1);
        cur ^= 1;
        sk *= 0.9;
    }

    softmin_kernel<1><<<sgrid, 256, 0, stream>>>(ws, cur, 0.0f, 0.0f, 0);

    reduce_kernel<<<1, 1024, 0, stream>>>(ws, out);
}

// Round 15
// 18825.850 us; speedup vs baseline: 5.4770x; 1.0402x over previous
//
#include <hip/hip_runtime.h>
#include <math.h>

#define NPTS   8192
#define NB     2
#define NROWS  (NB*NPTS)       // 16384 points per cloud (B=2 x 8192)
#define ROWS_PER_WAVE  8
#define WAVES_PER_BLOCK 4
#define ROWS_PER_BLOCK (ROWS_PER_WAVE*WAVES_PER_BLOCK)   // 32
#define BLURF  0.001f
#define LOG2E  1.4426950408889634f
#define LN2F   0.6931471805599453f
#define BLOGF  (-9.010913347279288f)   // -log(8192)
#define DEFER_THR 8.0f
#define SKIP_THR  30.0f
#define PRUNE_K   48

typedef float v2f __attribute__((ext_vector_type(2)));

#if __has_builtin(__builtin_amdgcn_sqrtf)
#define FAST_SQRT(x) __builtin_amdgcn_sqrtf(x)
#else
#define FAST_SQRT(x) sqrtf(x)
#endif
#if __has_builtin(__builtin_amdgcn_exp2f)
#define RAW_EXP2(x) __builtin_amdgcn_exp2f(x)
#else
#define RAW_EXP2(x) exp2f(x)
#endif
#if __has_builtin(__builtin_amdgcn_logf)
#define RAW_LOG2(x) __builtin_amdgcn_logf(x)
#else
#define RAW_LOG2(x) log2f(x)
#endif
#if __has_builtin(__builtin_elementwise_max)
#define PKMAX(a,b) __builtin_elementwise_max(a,b)
#else
static __device__ __forceinline__ v2f PKMAX(v2f a, v2f b){ v2f r; r.x=fmaxf(a.x,b.x); r.y=fmaxf(a.y,b.y); return r; }
#endif

// ---- workspace layout (floats). Total = 16 + 12*NROWS = 196624 floats (786 KB)
#define WS_DIAM 0
#define WS_FA   16
#define WS_GA   (WS_FA + NROWS)
#define WS_XX   (WS_GA + NROWS)      // x-cloud coords SoA (X,Y,Z segments of NROWS)
#define WS_XY   (WS_XX + 3*NROWS)    // y-cloud coords SoA
#define WS_WXA  (WS_XY + 3*NROWS)    // folded f (cols of dir1), buffers A/B
#define WS_WXB  (WS_WXA + NROWS)
#define WS_WYA  (WS_WXB + NROWS)     // folded g (cols of dir0), buffers A/B
#define WS_WYB  (WS_WYA + NROWS)

// ---------------------------------------------------------------- diameter
__global__ __launch_bounds__(1024) void minmax_kernel(
    const float* __restrict__ x, const float* __restrict__ y,
    float* __restrict__ diam_out)
{
    int tid = threadIdx.x;
    float mx[3] = {-INFINITY, -INFINITY, -INFINITY};
    float mn[3] = { INFINITY,  INFINITY,  INFINITY};
    for (int p = tid; p < NROWS; p += 1024) {
        #pragma unroll
        for (int d = 0; d < 3; ++d) {
            float a = x[p*3+d], b = y[p*3+d];
            mx[d] = fmaxf(mx[d], fmaxf(a, b));
            mn[d] = fminf(mn[d], fminf(a, b));
        }
    }
    #pragma unroll
    for (int off = 32; off >= 1; off >>= 1) {
        #pragma unroll
        for (int d = 0; d < 3; ++d) {
            mx[d] = fmaxf(mx[d], __shfl_xor(mx[d], off));
            mn[d] = fminf(mn[d], __shfl_xor(mn[d], off));
        }
    }
    __shared__ float smx[16][3], smn[16][3];
    int wid = tid >> 6, lane = tid & 63;
    if (lane == 0) {
        #pragma unroll
        for (int d = 0; d < 3; ++d) { smx[wid][d] = mx[d]; smn[wid][d] = mn[d]; }
    }
    __syncthreads();
    if (tid == 0) {
        float dm = 0.0f;
        #pragma unroll
        for (int d = 0; d < 3; ++d) {
            float a = -INFINITY, b = INFINITY;
            for (int w = 0; w < 16; ++w) {
                a = fmaxf(a, smx[w][d]); b = fminf(b, smn[w][d]);
            }
            dm = fmaxf(dm, a - b);
        }
        diam_out[0] = dm;
    }
}

// ----------------- Morton-cell counting sort + SoA pack + W init ----------
static __device__ __forceinline__ int morton3(int cx, int cy, int cz){
    int m = 0;
    #pragma unroll
    for (int b = 0; b < 3; ++b)
        m |= (((cx>>b)&1)<<(3*b)) | (((cy>>b)&1)<<(3*b+1)) | (((cz>>b)&1)<<(3*b+2));
    return m;
}

__global__ __launch_bounds__(1024) void sort_pack_kernel(
    const float* __restrict__ x, const float* __restrict__ y,
    float* __restrict__ ws)
{
    const int g = blockIdx.x;
    const int cloud = g >> 1, b = g & 1;
    const float* src = (cloud ? y : x) + b * NPTS * 3;
    const int soa = cloud ? WS_XY : WS_XX;
    float* DX = ws + soa + b * NPTS;
    float* DY = ws + soa + NROWS + b * NPTS;
    float* DZ = ws + soa + 2*NROWS + b * NPTS;
    float* DW = ws + (cloud ? WS_WYA : WS_WXA) + b * NPTS;

    const int tid = threadIdx.x;
    __shared__ float wmn[16][3], wmx[16][3];
    __shared__ float sbb[6];
    __shared__ int   hist[512];
    __shared__ int   offs[512];

    float mn[3] = { INFINITY,  INFINITY,  INFINITY};
    float mx[3] = {-INFINITY, -INFINITY, -INFINITY};
    for (int p = tid; p < NPTS; p += 1024) {
        #pragma unroll
        for (int d = 0; d < 3; ++d) {
            float v = src[p*3+d];
            mn[d] = fminf(mn[d], v); mx[d] = fmaxf(mx[d], v);
        }
    }
    #pragma unroll
    for (int off = 32; off >= 1; off >>= 1) {
        #pragma unroll
        for (int d = 0; d < 3; ++d) {
            mn[d] = fminf(mn[d], __shfl_xor(mn[d], off));
            mx[d] = fmaxf(mx[d], __shfl_xor(mx[d], off));
        }
    }
    int wid = tid >> 6, lane = tid & 63;
    if (lane == 0) {
        #pragma unroll
        for (int d = 0; d < 3; ++d) { wmn[wid][d] = mn[d]; wmx[wid][d] = mx[d]; }
    }
    if (tid < 512) hist[tid] = 0;
    __syncthreads();
    if (tid == 0) {
        #pragma unroll
        for (int d = 0; d < 3; ++d) {
            float a = INFINITY, bx = -INFINITY;
            for (int w = 0; w < 16; ++w) { a = fminf(a, wmn[w][d]); bx = fmaxf(bx, wmx[w][d]); }
            sbb[d] = a; sbb[3+d] = bx;
        }
    }
    __syncthreads();
    float bmn0 = sbb[0], bmn1 = sbb[1], bmn2 = sbb[2];
    float sc0 = 7.999f / fmaxf(sbb[3]-sbb[0], 1e-9f);
    float sc1 = 7.999f / fmaxf(sbb[4]-sbb[1], 1e-9f);
    float sc2 = 7.999f / fmaxf(sbb[5]-sbb[2], 1e-9f);

    for (int p = tid; p < NPTS; p += 1024) {
        int cx = (int)((src[p*3+0]-bmn0)*sc0);
        int cy = (int)((src[p*3+1]-bmn1)*sc1);
        int cz = (int)((src[p*3+2]-bmn2)*sc2);
        cx = min(max(cx,0),7); cy = min(max(cy,0),7); cz = min(max(cz,0),7);
        atomicAdd(&hist[morton3(cx,cy,cz)], 1);
    }
    __syncthreads();
    if (tid == 0) {
        int run = 0;
        for (int c = 0; c < 512; ++c) { offs[c] = run; run += hist[c]; }
    }
    __syncthreads();
    for (int p = tid; p < NPTS; p += 1024) {
        float px = src[p*3+0], py = src[p*3+1], pz = src[p*3+2];
        int cx = (int)((px-bmn0)*sc0);
        int cy = (int)((py-bmn1)*sc1);
        int cz = (int)((pz-bmn2)*sc2);
        cx = min(max(cx,0),7); cy = min(max(cy,0),7); cz = min(max(cz,0),7);
        int pos = atomicAdd(&offs[morton3(cx,cy,cz)], 1);
        DX[pos] = px; DY[pos] = py; DZ[pos] = pz;
        DW[pos] = BLOGF * LOG2E;
    }
}

// ------------------------------------------------------------- softmin pass
// out[b,i] = -eps*ln2*log2( sum_j 2^{W[j] - ||p_i - q_j||*log2e/eps} )
// PRUNE=1: per-128-col quantum SPHERE check (wave-uniform row bounding sphere
// + lazy scalar crmin). ~10 pk-ops/quantum, no state live across the branch.
template<int PRUNE>
__global__ __launch_bounds__(256, 4) void softmin_kernel(
    float* __restrict__ ws, int cur,
    float scale_k, float scale_next, int do_avg)
{
    const int dir = blockIdx.z;

    const float diam      = ws[WS_DIAM];
    const float eps       = fmaxf(diam * scale_k, BLURF);
    const float nie2      = -LOG2E / eps;
    const float ipt       = eps * LN2F;
    const float eps_next  = fmaxf(diam * scale_next, BLURF);
    const float ien_log2e = LOG2E / eps_next;

    const int tid = threadIdx.x, lane = tid & 63, wid = tid >> 6;
    const int i0  = blockIdx.x * ROWS_PER_BLOCK;
    const int b   = i0 >> 13;
    const int rowbase = i0 + wid * ROWS_PER_WAVE;

    const int rbase = dir ? WS_XY : WS_XX;
    const float* RX = ws + rbase;
    const float* RY = ws + rbase + NROWS;
    const float* RZ = ws + rbase + 2*NROWS;
    const int cbase = dir ? WS_XX : WS_XY;
    const v2f* CX = ((const v2f*)(ws + cbase          )) + b*(NPTS/2);
    const v2f* CY = ((const v2f*)(ws + cbase +   NROWS)) + b*(NPTS/2);
    const v2f* CZ = ((const v2f*)(ws + cbase + 2*NROWS)) + b*(NPTS/2);
    const int wcur_off = dir ? (cur ? WS_WXB : WS_WXA) : (cur ? WS_WYB : WS_WYA);
    const int wnxt_off = dir ? (cur ? WS_WYA : WS_WYB) : (cur ? WS_WXA : WS_WXB);
    const v2f* CW = ((const v2f*)(ws + wcur_off)) + b*(NPTS/2);
    float* Wnxt = ws + wnxt_off;
    float* outf = ws + (dir ? WS_GA : WS_FA);

    float px[ROWS_PER_WAVE], py[ROWS_PER_WAVE], pz[ROWS_PER_WAVE];
    #pragma unroll
    for (int r = 0; r < ROWS_PER_WAVE; ++r) {
        px[r] = RX[rowbase + r]; py[r] = RY[rowbase + r]; pz[r] = RZ[rowbase + r];
    }

    v2f m2[ROWS_PER_WAVE], s2[ROWS_PER_WAVE];
    #pragma unroll
    for (int r = 0; r < ROWS_PER_WAVE; ++r) {
        m2[r] = (v2f){-INFINITY,-INFINITY}; s2[r] = (v2f){0.0f,0.0f};
    }

    const v2f nie2v = {nie2, nie2};
    const v2f zv = {0.0f, 0.0f};

    if constexpr (PRUNE) {
        // wave-uniform bounding sphere of the 8 rows
        float x0=px[0],x1=px[0],y0=py[0],y1=py[0],z0=pz[0],z1=pz[0];
        #pragma unroll
        for (int r = 1; r < ROWS_PER_WAVE; ++r) {
            x0=fminf(x0,px[r]); x1=fmaxf(x1,px[r]);
            y0=fminf(y0,py[r]); y1=fmaxf(y1,py[r]);
            z0=fminf(z0,pz[r]); z1=fmaxf(z1,pz[r]);
        }
        const float ccx=0.5f*(x0+x1), ccy=0.5f*(y0+y1), ccz=0.5f*(z0+z1);
        const float rg = 0.5f*FAST_SQRT((x1-x0)*(x1-x0)+(y1-y0)*(y1-y0)+(z1-z0)*(z1-z0));
        float crmin = INFINITY;     // (SKIP_THR - min m2) * ipt, lazily updated

        for (int kk = 0; kk < NPTS/2; kk += 64) {   // 128 cols per quantum
            const int idx = kk + lane;
            const v2f Xk = CX[idx], Yk = CY[idx], Zk = CZ[idx], Wk = CW[idx];
            // sphere check: keep iff dist(center,col) < max(W*ipt+crmin,0)+rg
            v2f dxc = Xk - (v2f){ccx,ccx};
            v2f dyc = Yk - (v2f){ccy,ccy};
            v2f dzc = Zk - (v2f){ccz,ccz};
            v2f sqc = dxc*dxc + dyc*dyc + dzc*dzc;
            v2f targ = Wk * (v2f){ipt,ipt} + (v2f){crmin,crmin};
            v2f t = PKMAX(targ, zv);
            t = t + (v2f){rg,rg};
            v2f met = t*t - sqc;
            if (__any(fmaxf(met.x, met.y) > 0.0f)) {
                bool mupd = false;
                #pragma unroll
                for (int r = 0; r < ROWS_PER_WAVE; ++r) {
                    v2f dx = Xk - (v2f){px[r],px[r]};
                    v2f dy = Yk - (v2f){py[r],py[r]};
                    v2f dz = Zk - (v2f){pz[r],pz[r]};
                    v2f sq = dx*dx + dy*dy + dz*dz;
                    v2f c2; c2.x = FAST_SQRT(sq.x); c2.y = FAST_SQRT(sq.y);
                    v2f w2 = c2 * nie2v + Wk;
                    bool need = (w2.x > m2[r].x + DEFER_THR) | (w2.y > m2[r].y + DEFER_THR);
                    if (__any(need)) {
                        v2f mu = PKMAX(m2[r], w2);
                        v2f dm = m2[r] - mu;
                        v2f sc; sc.x = RAW_EXP2(dm.x); sc.y = RAW_EXP2(dm.y);
                        s2[r] = s2[r] * sc;
                        m2[r] = mu;
                        mupd = true;
                    }
                    v2f e = w2 - m2[r];
                    v2f ve; ve.x = RAW_EXP2(e.x); ve.y = RAW_EXP2(e.y);
                    s2[r] = s2[r] + ve;
                }
                if (mupd) {
                    float mm = fminf(m2[0].x, m2[0].y);
                    #pragma unroll
                    for (int r = 1; r < ROWS_PER_WAVE; ++r)
                        mm = fminf(mm, fminf(m2[r].x, m2[r].y));
                    crmin = (SKIP_THR - mm) * ipt;
                }
            }
        }
    } else {
        for (int c0 = 0; c0 < NPTS/2; c0 += 256) {     // 512 cols per iter
            v2f Xc[4], Yc[4], Zc[4], Wc[4];
            #pragma unroll
            for (int k = 0; k < 4; ++k) {
                int idx = c0 + k*64 + lane;
                Xc[k] = CX[idx]; Yc[k] = CY[idx]; Zc[k] = CZ[idx]; Wc[k] = CW[idx];
            }
            #pragma unroll
            for (int r = 0; r < ROWS_PER_WAVE; ++r) {
                const v2f prx = {px[r], px[r]}, pry = {py[r], py[r]}, prz = {pz[r], pz[r]};
                v2f w2[4];
                #pragma unroll
                for (int k = 0; k < 4; ++k) {
                    v2f dx = Xc[k] - prx, dy = Yc[k] - pry, dz = Zc[k] - prz;
                    v2f sq = dx*dx + dy*dy + dz*dz;
                    v2f c2; c2.x = FAST_SQRT(sq.x); c2.y = FAST_SQRT(sq.y);
                    w2[k] = c2 * nie2v + Wc[k];
                }
                v2f gm = PKMAX(PKMAX(w2[0], w2[1]), PKMAX(w2[2], w2[3]));
                bool need = (gm.x > m2[r].x + DEFER_THR) | (gm.y > m2[r].y + DEFER_THR);
                if (__any(need)) {
                    v2f mu = PKMAX(m2[r], gm);
                    v2f dm = m2[r] - mu;
                    v2f sc; sc.x = RAW_EXP2(dm.x); sc.y = RAW_EXP2(dm.y);
                    s2[r] = s2[r] * sc;
                    m2[r] = mu;
                }
                v2f e0 = w2[0] - m2[r], e1 = w2[1] - m2[r], e2 = w2[2] - m2[r], e3 = w2[3] - m2[r];
                v2f v0, v1, v2, v3;
                v0.x = RAW_EXP2(e0.x); v0.y = RAW_EXP2(e0.y);
                v1.x = RAW_EXP2(e1.x); v1.y = RAW_EXP2(e1.y);
                v2.x = RAW_EXP2(e2.x); v2.y = RAW_EXP2(e2.y);
                v3.x = RAW_EXP2(e3.x); v3.y = RAW_EXP2(e3.y);
                s2[r] = s2[r] + ((v0 + v1) + (v2 + v3));
            }
        }
    }

    // merge packed halves, then 64-lane butterfly
    #pragma unroll
    for (int r = 0; r < ROWS_PER_WAVE; ++r) {
        float mm = fmaxf(m2[r].x, m2[r].y);
        float ss = s2[r].x * RAW_EXP2(m2[r].x - mm) + s2[r].y * RAW_EXP2(m2[r].y - mm);
        #pragma unroll
        for (int off = 32; off >= 1; off >>= 1) {
            float mo = __shfl_xor(mm, off);
            float so = __shfl_xor(ss, off);
            float mu = fmaxf(mm, mo);
            ss = fmaf(ss, RAW_EXP2(mm-mu), so * RAW_EXP2(mo-mu));
            mm = mu;
        }
        if (lane == 0) {
            float res = -eps * LN2F * (mm + RAW_LOG2(ss));
            int oidx = rowbase + r;
            if (do_avg) res = 0.5f * (outf[oidx] + res);   // element owned by this thread
            outf[oidx] = res;
            Wnxt[oidx] = fmaf(res, ien_log2e, BLOGF * LOG2E);  // fold for next pass
        }
    }
}

// ----------------------------------------------------------------- reduce
__global__ __launch_bounds__(1024) void reduce_kernel(
    const float* __restrict__ ws, float* __restrict__ out)
{
    const float* f = ws + WS_FA;
    const float* g = ws + WS_GA;
    int tid = threadIdx.x;
    float acc = 0.0f;
    for (int i = tid; i < NROWS; i += 1024) acc += f[i] + g[i];
    #pragma unroll
    for (int off = 32; off >= 1; off >>= 1) acc += __shfl_xor(acc, off);
    __shared__ float sw[16];
    int wid = tid >> 6, lane = tid & 63;
    if (lane == 0) sw[wid] = acc;
    __syncthreads();
    if (tid == 0) {
        float t = 0.0f;
        for (int w = 0; w < 16; ++w) t += sw[w];
        out[0] = t * (1.0f / (float)NROWS);   // mean over B of (sum a*f + sum b*g)
    }
}

// ----------------------------------------------------------------- launch
extern "C" void kernel_launch(void* const* d_in, const int* in_sizes, int n_in,
                              void* d_out, int out_size, void* d_ws, size_t ws_size,
                              hipStream_t stream)
{
    const float* x = (const float*)d_in[0];
    const float* y = (const float*)d_in[1];
    float* out = (float*)d_out;
    float* ws  = (float*)d_ws;

    minmax_kernel<<<1, 1024, 0, stream>>>(x, y, ws + WS_DIAM);
    sort_pack_kernel<<<4, 1024, 0, stream>>>(x, y, ws);

    dim3 sgrid(NROWS/ROWS_PER_BLOCK, 1, 2);   // 512 x 1 x 2
    int cur = 0;

    softmin_kernel<0><<<sgrid, 256, 0, stream>>>(ws, cur, 1.0f, 1.0f, 0);
    cur ^= 1;

    double sk = 1.0;
    for (int k = 0; k < 96; ++k) {
        float sn = (k < 95) ? (float)(sk * 0.9) : 0.0f;   // last folds at blur
        if (k >= PRUNE_K)
            softmin_kernel<1><<<sgrid, 256, 0, stream>>>(ws, cur, (float)sk, sn, 1);
        else
            softmin_kernel<0><<<sgrid, 256, 0, stream>>>(ws, cur, (float)sk, sn, 1);
        cur ^= 1;
        sk *= 0.9;
    }

    softmin_kernel<1><<<sgrid, 256, 0, stream>>>(ws, cur, 0.0f, 0.0f, 0);

    reduce_kernel<<<1, 1024, 0, stream>>>(ws, out);
}